// Round 1
// baseline (178.701 us; speedup 1.0000x reference)
//
#include <hip/hip_runtime.h>

#define BB 4
#define NN 2048
#define DD 4
#define ROWS 4
#define BLOCK 256

__global__ __launch_bounds__(BLOCK) void sincos_theta(const float* __restrict__ theta,
                                                      float* __restrict__ sArr,
                                                      float* __restrict__ cArr) {
    const int idx = blockIdx.x * BLOCK + threadIdx.x;   // B*N*D = 32768 total
    const float x = theta[idx];
    float s, c;
    __sincosf(x, &s, &c);
    sArr[idx] = s;
    cArr[idx] = c;
}

__global__ __launch_bounds__(BLOCK) void kuramoto_main(
    const float* __restrict__ theta,
    const float* __restrict__ gam,
    const float* __restrict__ aff,
    const float* __restrict__ alp,
    const float* __restrict__ omega,
    const float* __restrict__ kappa,
    const float* __restrict__ bias,
    const float* __restrict__ sArr,
    const float* __restrict__ cArr,
    float* __restrict__ out)
{
    const int tid = threadIdx.x;
    const int blk = blockIdx.x;
    const int rowBlocks = NN / ROWS;            // 512 blocks per batch
    const int b  = blk / rowBlocks;
    const int i0 = (blk % rowBlocks) * ROWS;

    const float* __restrict__ aff_b = aff + (size_t)b * NN * NN;
    const float* __restrict__ alp_b = alp + (size_t)b * NN * NN;
    const float4* __restrict__ s4 = (const float4*)sArr + (size_t)b * NN;
    const float4* __restrict__ c4 = (const float4*)cArr + (size_t)b * NN;

    float accU[ROWS][DD];
    float accV[ROWS][DD];
    #pragma unroll
    for (int r = 0; r < ROWS; ++r)
        #pragma unroll
        for (int d = 0; d < DD; ++d) { accU[r][d] = 0.f; accV[r][d] = 0.f; }

    for (int jj = 0; jj < NN / BLOCK; ++jj) {
        const int j = tid + jj * BLOCK;
        const float4 sj = s4[j];
        const float4 cj = c4[j];
        #pragma unroll
        for (int r = 0; r < ROWS; ++r) {
            const size_t off = (size_t)(i0 + r) * NN + j;   // i*N + j (batch-free)
            const float a  = aff_b[off];
            const float al = alp_b[off] + bias[off];
            float sa, ca;
            __sincosf(al, &sa, &ca);
            const float wc = a * ca;
            const float ws = a * sa;
            accU[r][0] = fmaf(wc, sj.x, fmaf(-ws, cj.x, accU[r][0]));
            accU[r][1] = fmaf(wc, sj.y, fmaf(-ws, cj.y, accU[r][1]));
            accU[r][2] = fmaf(wc, sj.z, fmaf(-ws, cj.z, accU[r][2]));
            accU[r][3] = fmaf(wc, sj.w, fmaf(-ws, cj.w, accU[r][3]));
            accV[r][0] = fmaf(wc, cj.x, fmaf(ws, sj.x, accV[r][0]));
            accV[r][1] = fmaf(wc, cj.y, fmaf(ws, sj.y, accV[r][1]));
            accV[r][2] = fmaf(wc, cj.z, fmaf(ws, sj.z, accV[r][2]));
            accV[r][3] = fmaf(wc, cj.w, fmaf(ws, sj.w, accV[r][3]));
        }
    }

    // ---- reduction: 32 partials/thread -> per-wave shuffle -> LDS -> 16-thread epilogue
    __shared__ float red[BLOCK / 64][ROWS * 2 * DD];   // [4][32]
    const int wave = tid >> 6;
    const int lane = tid & 63;

    #pragma unroll
    for (int r = 0; r < ROWS; ++r) {
        #pragma unroll
        for (int d = 0; d < DD; ++d) {
            float u = accU[r][d];
            float v = accV[r][d];
            #pragma unroll
            for (int off = 32; off >= 1; off >>= 1) {
                u += __shfl_down(u, off, 64);
                v += __shfl_down(v, off, 64);
            }
            if (lane == 0) {
                red[wave][r * 2 * DD + d]      = u;
                red[wave][r * 2 * DD + DD + d] = v;
            }
        }
    }
    __syncthreads();

    if (tid < ROWS * DD) {
        const int r = tid >> 2;
        const int d = tid & 3;
        float U = 0.f, V = 0.f;
        #pragma unroll
        for (int w = 0; w < BLOCK / 64; ++w) {
            U += red[w][r * 2 * DD + d];
            V += red[w][r * 2 * DD + DD + d];
        }
        const int i = i0 + r;
        const int idx = (b * NN + i) * DD + d;
        const float s_i = sArr[idx];
        const float c_i = cArr[idx];
        const float coup = (1.0f / (float)NN) * (c_i * U - s_i * V);
        const float th = theta[idx];
        const float o  = omega[i * DD + d];
        const float k  = kappa[i * DD + d];
        // DT = 1, COUPLING = 1
        out[idx] = th + o + k * (gam[idx] - th) + coup;
    }
}

extern "C" void kernel_launch(void* const* d_in, const int* in_sizes, int n_in,
                              void* d_out, int out_size, void* d_ws, size_t ws_size,
                              hipStream_t stream) {
    const float* theta = (const float*)d_in[0];
    const float* gam   = (const float*)d_in[1];
    const float* aff   = (const float*)d_in[2];
    const float* alp   = (const float*)d_in[3];
    const float* omega = (const float*)d_in[4];
    const float* kappa = (const float*)d_in[5];
    const float* bias  = (const float*)d_in[6];
    float* out  = (float*)d_out;

    float* sArr = (float*)d_ws;                 // [B*N*D]
    float* cArr = sArr + BB * NN * DD;          // [B*N*D]  (512 KB total << ws)

    sincos_theta<<<(BB * NN * DD) / BLOCK, BLOCK, 0, stream>>>(theta, sArr, cArr);
    kuramoto_main<<<(BB * NN) / ROWS, BLOCK, 0, stream>>>(
        theta, gam, aff, alp, omega, kappa, bias, sArr, cArr, out);
}

// Round 2
// 178.241 us; speedup vs baseline: 1.0026x; 1.0026x over previous
//
#include <hip/hip_runtime.h>

#define BB 4
#define NN 2048
#define DD 4
#define ROWS 2
#define BLOCK 256
#define QPT 4                        // consecutive j's per thread (one float4 quad)
#define JITER (NN / (BLOCK * QPT))   // 2

typedef float f4 __attribute__((ext_vector_type(4)));

__global__ __launch_bounds__(BLOCK) void sincos_theta(const float* __restrict__ theta,
                                                      float* __restrict__ sArr,
                                                      float* __restrict__ cArr) {
    const int idx = blockIdx.x * BLOCK + threadIdx.x;   // B*N*D = 32768 total
    const float x = theta[idx];
    float s, c;
    __sincosf(x, &s, &c);
    sArr[idx] = s;
    cArr[idx] = c;
}

__global__ __launch_bounds__(BLOCK) void kuramoto_main(
    const float* __restrict__ theta,
    const float* __restrict__ gam,
    const float* __restrict__ aff,
    const float* __restrict__ alp,
    const float* __restrict__ omega,
    const float* __restrict__ kappa,
    const float* __restrict__ bias,
    const float* __restrict__ sArr,
    const float* __restrict__ cArr,
    float* __restrict__ out)
{
    const int tid = threadIdx.x;
    const int blk = blockIdx.x;
    const int rowBlocks = NN / ROWS;            // 1024 blocks per batch
    const int b  = blk / rowBlocks;
    const int i0 = (blk % rowBlocks) * ROWS;

    const f4* __restrict__ aff4 = (const f4*)(aff + (size_t)b * NN * NN);
    const f4* __restrict__ alp4 = (const f4*)(alp + (size_t)b * NN * NN);
    const f4* __restrict__ bia4 = (const f4*)bias;
    const f4* __restrict__ s4   = (const f4*)sArr + (size_t)b * NN;
    const f4* __restrict__ c4   = (const f4*)cArr + (size_t)b * NN;

    float accU[ROWS][DD];
    float accV[ROWS][DD];
    #pragma unroll
    for (int r = 0; r < ROWS; ++r)
        #pragma unroll
        for (int d = 0; d < DD; ++d) { accU[r][d] = 0.f; accV[r][d] = 0.f; }

    #pragma unroll
    for (int jj = 0; jj < JITER; ++jj) {
        const int q  = jj * BLOCK + tid;        // quad index along j
        const int j0 = q * QPT;

        // ---- load phase: all VMEM issued before any compute ----
        f4 av[ROWS], lv[ROWS], bv[ROWS];
        #pragma unroll
        for (int r = 0; r < ROWS; ++r) {
            const size_t qo = (size_t)(i0 + r) * (NN / QPT) + q;
            av[r] = __builtin_nontemporal_load(&aff4[qo]);   // streamed, no reuse
            lv[r] = __builtin_nontemporal_load(&alp4[qo]);   // streamed, no reuse
            bv[r] = bia4[qo];                                // reused across batches
        }
        f4 sj[QPT], cj[QPT];
        #pragma unroll
        for (int u = 0; u < QPT; ++u) { sj[u] = s4[j0 + u]; cj[u] = c4[j0 + u]; }

        // ---- compute phase ----
        #pragma unroll
        for (int r = 0; r < ROWS; ++r) {
            const f4 alr = lv[r] + bv[r];
            const float aA[4] = {av[r].x, av[r].y, av[r].z, av[r].w};
            const float lA[4] = {alr.x, alr.y, alr.z, alr.w};
            #pragma unroll
            for (int u = 0; u < QPT; ++u) {
                float sa, ca;
                __sincosf(lA[u], &sa, &ca);
                const float wc = aA[u] * ca;
                const float ws = aA[u] * sa;
                accU[r][0] = fmaf(wc, sj[u].x, fmaf(-ws, cj[u].x, accU[r][0]));
                accU[r][1] = fmaf(wc, sj[u].y, fmaf(-ws, cj[u].y, accU[r][1]));
                accU[r][2] = fmaf(wc, sj[u].z, fmaf(-ws, cj[u].z, accU[r][2]));
                accU[r][3] = fmaf(wc, sj[u].w, fmaf(-ws, cj[u].w, accU[r][3]));
                accV[r][0] = fmaf(wc, cj[u].x, fmaf(ws, sj[u].x, accV[r][0]));
                accV[r][1] = fmaf(wc, cj[u].y, fmaf(ws, sj[u].y, accV[r][1]));
                accV[r][2] = fmaf(wc, cj[u].z, fmaf(ws, sj[u].z, accV[r][2]));
                accV[r][3] = fmaf(wc, cj[u].w, fmaf(ws, sj[u].w, accV[r][3]));
            }
        }
    }

    // ---- reduction: per-wave shuffle -> LDS -> 8-thread epilogue ----
    __shared__ float red[BLOCK / 64][ROWS * 2 * DD];   // [4][16]
    const int wave = tid >> 6;
    const int lane = tid & 63;

    #pragma unroll
    for (int r = 0; r < ROWS; ++r) {
        #pragma unroll
        for (int d = 0; d < DD; ++d) {
            float u = accU[r][d];
            float v = accV[r][d];
            #pragma unroll
            for (int off = 32; off >= 1; off >>= 1) {
                u += __shfl_down(u, off, 64);
                v += __shfl_down(v, off, 64);
            }
            if (lane == 0) {
                red[wave][r * 2 * DD + d]      = u;
                red[wave][r * 2 * DD + DD + d] = v;
            }
        }
    }
    __syncthreads();

    if (tid < ROWS * DD) {
        const int r = tid >> 2;
        const int d = tid & 3;
        float U = 0.f, V = 0.f;
        #pragma unroll
        for (int w = 0; w < BLOCK / 64; ++w) {
            U += red[w][r * 2 * DD + d];
            V += red[w][r * 2 * DD + DD + d];
        }
        const int i = i0 + r;
        const int idx = (b * NN + i) * DD + d;
        const float s_i = sArr[idx];
        const float c_i = cArr[idx];
        const float coup = (1.0f / (float)NN) * (c_i * U - s_i * V);
        const float th = theta[idx];
        const float o  = omega[i * DD + d];
        const float k  = kappa[i * DD + d];
        // DT = 1, COUPLING = 1
        out[idx] = th + o + k * (gam[idx] - th) + coup;
    }
}

extern "C" void kernel_launch(void* const* d_in, const int* in_sizes, int n_in,
                              void* d_out, int out_size, void* d_ws, size_t ws_size,
                              hipStream_t stream) {
    const float* theta = (const float*)d_in[0];
    const float* gam   = (const float*)d_in[1];
    const float* aff   = (const float*)d_in[2];
    const float* alp   = (const float*)d_in[3];
    const float* omega = (const float*)d_in[4];
    const float* kappa = (const float*)d_in[5];
    const float* bias  = (const float*)d_in[6];
    float* out  = (float*)d_out;

    float* sArr = (float*)d_ws;                 // [B*N*D]
    float* cArr = sArr + BB * NN * DD;          // [B*N*D]

    sincos_theta<<<(BB * NN * DD) / BLOCK, BLOCK, 0, stream>>>(theta, sArr, cArr);
    kuramoto_main<<<(BB * NN) / ROWS, BLOCK, 0, stream>>>(
        theta, gam, aff, alp, omega, kappa, bias, sArr, cArr, out);
}

// Round 3
// 173.242 us; speedup vs baseline: 1.0315x; 1.0289x over previous
//
#include <hip/hip_runtime.h>

#define BB 4
#define NN 2048
#define DD 4
#define QQ (NN / 4)          // 512 quads along j
#define BLOCK 256
#define JIT (QQ / 64)        // 8 j-iterations per lane

typedef float f4 __attribute__((ext_vector_type(4)));
typedef _Float16 h8 __attribute__((ext_vector_type(8)));

// ---------------- precompute: sincos(theta) -> fp32 arrays (epilogue) + fp16 quad-transposed (main loop)
// scT layout: [b][d][q] -> 8 halves {s(j0),c(j0),s(j1),c(j1),s(j2),c(j2),s(j3),c(j3)}, j=4q+u
__global__ __launch_bounds__(BLOCK) void precomp(const float* __restrict__ theta,
                                                 float* __restrict__ sArr,
                                                 float* __restrict__ cArr,
                                                 h8* __restrict__ scT) {
    const int t = blockIdx.x * BLOCK + threadIdx.x;     // [0, B*QQ) = 2048
    const int b = t / QQ, q = t % QQ;
    const f4* theta4 = (const f4*)theta;
    f4* s4 = (f4*)sArr;
    f4* c4 = (f4*)cArr;

    float s[4][4], c[4][4];                              // [u][d]
    #pragma unroll
    for (int u = 0; u < 4; ++u) {
        const f4 th = theta4[(size_t)b * NN + 4 * q + u];
        const float thA[4] = {th.x, th.y, th.z, th.w};
        #pragma unroll
        for (int d = 0; d < 4; ++d) __sincosf(thA[d], &s[u][d], &c[u][d]);
    }
    #pragma unroll
    for (int u = 0; u < 4; ++u) {
        f4 sv, cv;
        sv.x = s[u][0]; sv.y = s[u][1]; sv.z = s[u][2]; sv.w = s[u][3];
        cv.x = c[u][0]; cv.y = c[u][1]; cv.z = c[u][2]; cv.w = c[u][3];
        s4[(size_t)b * NN + 4 * q + u] = sv;
        c4[(size_t)b * NN + 4 * q + u] = cv;
    }
    #pragma unroll
    for (int d = 0; d < 4; ++d) {
        h8 w;
        #pragma unroll
        for (int u = 0; u < 4; ++u) {
            w[2 * u]     = (_Float16)s[u][d];
            w[2 * u + 1] = (_Float16)c[u][d];
        }
        scT[((size_t)b * 4 + d) * QQ + q] = w;
    }
}

// ---------------- main: 1024 blocks, 4 waves/block, wave owns 2 rows, lane owns j-quads
__global__ __launch_bounds__(BLOCK) void kuramoto_main(
    const float* __restrict__ theta,
    const float* __restrict__ gam,
    const float* __restrict__ aff,
    const float* __restrict__ alp,
    const float* __restrict__ omega,
    const float* __restrict__ kappa,
    const float* __restrict__ bias,
    const float* __restrict__ sArr,
    const float* __restrict__ cArr,
    const h8* __restrict__ scT,
    float* __restrict__ out)
{
    // XCD swizzle: batch-siblings (same rows, b=0..3) differ by 8 in blockIdx -> same XCD,
    // and sit within a 32-block window -> temporally close -> bias L2 reuse.
    const int x   = blockIdx.x;
    const int low = x & 31;
    const int b   = low >> 3;
    const int g   = (x >> 5) * 8 + (low & 7);           // row-group [0,256)
    const int i0  = g * 8;

    const int tid  = threadIdx.x;
    const int wave = tid >> 6;
    const int lane = tid & 63;
    const int r0   = i0 + 2 * wave;                      // this wave's first row

    const f4* aff4 = (const f4*)(aff + (size_t)b * NN * NN);
    const f4* alp4 = (const f4*)(alp + (size_t)b * NN * NN);
    const f4* bia4 = (const f4*)bias;
    const h8* scb  = scT + (size_t)b * 4 * QQ;

    float accU[2][4], accV[2][4];
    #pragma unroll
    for (int r = 0; r < 2; ++r)
        #pragma unroll
        for (int d = 0; d < 4; ++d) { accU[r][d] = 0.f; accV[r][d] = 0.f; }

    // double-buffered global streams
    f4 av[2][2], lv[2][2], bv[2][2];
    {
        const int q = lane;
        #pragma unroll
        for (int r = 0; r < 2; ++r) {
            const size_t qo = (size_t)(r0 + r) * QQ + q;
            av[0][r] = __builtin_nontemporal_load(&aff4[qo]);
            lv[0][r] = __builtin_nontemporal_load(&alp4[qo]);
            bv[0][r] = bia4[qo];
        }
    }

    #pragma unroll
    for (int jj = 0; jj < JIT; ++jj) {
        const int cur = jj & 1;
        const int nxt = cur ^ 1;
        const int q   = lane + 64 * jj;

        if (jj + 1 < JIT) {
            const int qn = lane + 64 * (jj + 1);
            #pragma unroll
            for (int r = 0; r < 2; ++r) {
                const size_t qo = (size_t)(r0 + r) * QQ + qn;
                av[nxt][r] = __builtin_nontemporal_load(&aff4[qo]);
                lv[nxt][r] = __builtin_nontemporal_load(&alp4[qo]);
                bv[nxt][r] = bia4[qo];
            }
        }

        // sc for this quad: 4 d-rows, converted once, reused by both rows
        float sj[4][4], cj[4][4];                        // [u][d]
        #pragma unroll
        for (int d = 0; d < 4; ++d) {
            const h8 w = scb[(size_t)d * QQ + q];
            #pragma unroll
            for (int u = 0; u < 4; ++u) {
                sj[u][d] = (float)w[2 * u];
                cj[u][d] = (float)w[2 * u + 1];
            }
        }

        #pragma unroll
        for (int r = 0; r < 2; ++r) {
            const f4 alr = lv[cur][r] + bv[cur][r];
            const float aA[4] = {av[cur][r].x, av[cur][r].y, av[cur][r].z, av[cur][r].w};
            const float lA[4] = {alr.x, alr.y, alr.z, alr.w};
            #pragma unroll
            for (int u = 0; u < 4; ++u) {
                float sa, ca;
                __sincosf(lA[u], &sa, &ca);
                const float wc = aA[u] * ca;
                const float ws = aA[u] * sa;
                #pragma unroll
                for (int d = 0; d < 4; ++d) {
                    accU[r][d] = fmaf(wc, sj[u][d], fmaf(-ws, cj[u][d], accU[r][d]));
                    accV[r][d] = fmaf(wc, cj[u][d], fmaf(ws, sj[u][d], accV[r][d]));
                }
            }
        }
    }

    // ---- wave-local shuffle reduction; no LDS, no barrier
    #pragma unroll
    for (int r = 0; r < 2; ++r)
        #pragma unroll
        for (int d = 0; d < 4; ++d) {
            float u = accU[r][d], v = accV[r][d];
            #pragma unroll
            for (int off = 32; off >= 1; off >>= 1) {
                u += __shfl_down(u, off, 64);
                v += __shfl_down(v, off, 64);
            }
            accU[r][d] = u; accV[r][d] = v;              // valid in lane 0
        }

    if (lane == 0) {
        const f4* theta4 = (const f4*)theta;
        const f4* gam4   = (const f4*)gam;
        const f4* om4    = (const f4*)omega;
        const f4* kp4    = (const f4*)kappa;
        const f4* s4     = (const f4*)sArr;
        const f4* c4     = (const f4*)cArr;
        f4* out4         = (f4*)out;
        #pragma unroll
        for (int r = 0; r < 2; ++r) {
            const int i = r0 + r;
            const size_t base = (size_t)b * NN + i;
            const f4 th = theta4[base];
            const f4 gm = gam4[base];
            const f4 om = om4[i];
            const f4 kp = kp4[i];
            const f4 si = s4[base];
            const f4 ci = c4[base];
            const float siA[4] = {si.x, si.y, si.z, si.w};
            const float ciA[4] = {ci.x, ci.y, ci.z, ci.w};
            const float thA[4] = {th.x, th.y, th.z, th.w};
            const float gmA[4] = {gm.x, gm.y, gm.z, gm.w};
            const float omA[4] = {om.x, om.y, om.z, om.w};
            const float kpA[4] = {kp.x, kp.y, kp.z, kp.w};
            f4 o;
            float oA[4];
            #pragma unroll
            for (int d = 0; d < 4; ++d) {
                const float coup = (1.0f / (float)NN) * (ciA[d] * accU[r][d] - siA[d] * accV[r][d]);
                oA[d] = thA[d] + omA[d] + kpA[d] * (gmA[d] - thA[d]) + coup;
            }
            o.x = oA[0]; o.y = oA[1]; o.z = oA[2]; o.w = oA[3];
            out4[base] = o;
        }
    }
}

extern "C" void kernel_launch(void* const* d_in, const int* in_sizes, int n_in,
                              void* d_out, int out_size, void* d_ws, size_t ws_size,
                              hipStream_t stream) {
    const float* theta = (const float*)d_in[0];
    const float* gam   = (const float*)d_in[1];
    const float* aff   = (const float*)d_in[2];
    const float* alp   = (const float*)d_in[3];
    const float* omega = (const float*)d_in[4];
    const float* kappa = (const float*)d_in[5];
    const float* bias  = (const float*)d_in[6];
    float* out  = (float*)d_out;

    float* sArr = (float*)d_ws;                          // [B*N*D] fp32
    float* cArr = sArr + BB * NN * DD;                   // [B*N*D] fp32
    h8*    scT  = (h8*)(cArr + BB * NN * DD);            // [B][4][QQ] fp16 pairs, 128 KB

    precomp<<<(BB * QQ) / BLOCK, BLOCK, 0, stream>>>(theta, sArr, cArr, scT);
    kuramoto_main<<<BB * (NN / 8), BLOCK, 0, stream>>>(
        theta, gam, aff, alp, omega, kappa, bias, sArr, cArr, scT, out);
}

// Round 4
// 169.557 us; speedup vs baseline: 1.0539x; 1.0217x over previous
//
#include <hip/hip_runtime.h>

#define BB 4
#define NN 2048
#define DD 4
#define QQ (NN / 4)          // 512 quads along j
#define BLOCK 256
#define JIT (QQ / 64)        // 8 j-iterations per lane

typedef float f4 __attribute__((ext_vector_type(4)));
typedef _Float16 h8 __attribute__((ext_vector_type(8)));

// ---------------- precompute: sincos(theta) -> fp32 arrays (epilogue) + fp16 quad-packed (main loop)
// scT layout: [b][d][q] -> 8 halves {s(j0),c(j0),s(j1),c(j1),s(j2),c(j2),s(j3),c(j3)}, j=4q+u
__global__ __launch_bounds__(BLOCK) void precomp(const float* __restrict__ theta,
                                                 float* __restrict__ sArr,
                                                 float* __restrict__ cArr,
                                                 h8* __restrict__ scT) {
    const int t = blockIdx.x * BLOCK + threadIdx.x;     // [0, B*QQ) = 2048
    const int b = t / QQ, q = t % QQ;
    const f4* theta4 = (const f4*)theta;
    f4* s4 = (f4*)sArr;
    f4* c4 = (f4*)cArr;

    float s[4][4], c[4][4];                              // [u][d]
    #pragma unroll
    for (int u = 0; u < 4; ++u) {
        const f4 th = theta4[(size_t)b * NN + 4 * q + u];
        #pragma unroll
        for (int d = 0; d < 4; ++d) __sincosf(th[d], &s[u][d], &c[u][d]);
    }
    #pragma unroll
    for (int u = 0; u < 4; ++u) {
        f4 sv, cv;
        #pragma unroll
        for (int d = 0; d < 4; ++d) { sv[d] = s[u][d]; cv[d] = c[u][d]; }
        s4[(size_t)b * NN + 4 * q + u] = sv;
        c4[(size_t)b * NN + 4 * q + u] = cv;
    }
    #pragma unroll
    for (int d = 0; d < 4; ++d) {
        h8 w;
        #pragma unroll
        for (int u = 0; u < 4; ++u) {
            w[2 * u]     = (_Float16)s[u][d];
            w[2 * u + 1] = (_Float16)c[u][d];
        }
        scT[((size_t)b * 4 + d) * QQ + q] = w;
    }
}

// ---------------- main: 2048 blocks, 4 waves/block, ONE row per wave, sc in LDS
__global__ __launch_bounds__(BLOCK, 5) void kuramoto_main(
    const float* __restrict__ theta,
    const float* __restrict__ gam,
    const float* __restrict__ aff,
    const float* __restrict__ alp,
    const float* __restrict__ omega,
    const float* __restrict__ kappa,
    const float* __restrict__ bias,
    const float* __restrict__ sArr,
    const float* __restrict__ cArr,
    const h8* __restrict__ scT,
    float* __restrict__ out)
{
    // XCD swizzle: batch-siblings (same rows, b=0..3) within a 32-block window
    // land on the same XCD close in time -> bias L2 reuse.
    const int x   = blockIdx.x;                          // [0, 2048)
    const int low = x & 31;
    const int b   = low >> 3;
    const int g   = (x >> 5) * 8 + (low & 7);            // row-group [0, 512)
    const int i0  = g * 4;

    const int tid  = threadIdx.x;
    const int wave = tid >> 6;
    const int lane = tid & 63;
    const int i    = i0 + wave;                          // this wave's row

    // ---- stage this batch's sincos table into LDS (32 KB) ----
    __shared__ h8 lsc[4 * QQ];
    {
        const h8* gsc = scT + (size_t)b * 4 * QQ;
        #pragma unroll
        for (int k = 0; k < (4 * QQ) / BLOCK; ++k)
            lsc[tid + BLOCK * k] = gsc[tid + BLOCK * k];
    }
    __syncthreads();

    const f4* arow = (const f4*)(aff + (size_t)b * NN * NN) + (size_t)i * QQ;
    const f4* lrow = (const f4*)(alp + (size_t)b * NN * NN) + (size_t)i * QQ;
    const f4* brow = (const f4*)bias + (size_t)i * QQ;

    f4 accU = {0.f, 0.f, 0.f, 0.f};
    f4 accV = {0.f, 0.f, 0.f, 0.f};

    // depth-1 double-buffered global streams
    f4 av[2], lv[2], bv[2];
    av[0] = __builtin_nontemporal_load(&arow[lane]);
    lv[0] = __builtin_nontemporal_load(&lrow[lane]);
    bv[0] = brow[lane];

    #pragma unroll
    for (int jj = 0; jj < JIT; ++jj) {
        const int cur = jj & 1;
        const int nxt = cur ^ 1;
        const int q   = lane + 64 * jj;

        if (jj + 1 < JIT) {
            const int qn = q + 64;
            av[nxt] = __builtin_nontemporal_load(&arow[qn]);
            lv[nxt] = __builtin_nontemporal_load(&lrow[qn]);
            bv[nxt] = brow[qn];
        }

        // sc for this quad from LDS: transpose [d][u-pairs] -> sj[u][d], cj[u][d]
        f4 sj[4], cj[4];
        #pragma unroll
        for (int d = 0; d < 4; ++d) {
            const h8 w = lsc[d * QQ + q];
            #pragma unroll
            for (int u = 0; u < 4; ++u) {
                sj[u][d] = (float)w[2 * u];
                cj[u][d] = (float)w[2 * u + 1];
            }
        }

        const f4 alr = lv[cur] + bv[cur];
        const f4 af  = av[cur];
        #pragma unroll
        for (int u = 0; u < 4; ++u) {
            float sa, ca;
            __sincosf(alr[u], &sa, &ca);
            const float wc = af[u] * ca;
            const float ws = af[u] * sa;
            accU += wc * sj[u] - ws * cj[u];
            accV += wc * cj[u] + ws * sj[u];
        }
    }

    // ---- wave-local shuffle reduction; no barrier needed ----
    #pragma unroll
    for (int off = 32; off >= 1; off >>= 1) {
        #pragma unroll
        for (int d = 0; d < 4; ++d) {
            accU[d] += __shfl_down(accU[d], off, 64);
            accV[d] += __shfl_down(accV[d], off, 64);
        }
    }

    if (lane == 0) {
        const f4* theta4 = (const f4*)theta;
        const f4* gam4   = (const f4*)gam;
        const f4* om4    = (const f4*)omega;
        const f4* kp4    = (const f4*)kappa;
        const f4* s4     = (const f4*)sArr;
        const f4* c4     = (const f4*)cArr;
        f4* out4         = (f4*)out;

        const size_t base = (size_t)b * NN + i;
        const f4 th = theta4[base];
        const f4 gm = gam4[base];
        const f4 om = om4[i];
        const f4 kp = kp4[i];
        const f4 si = s4[base];
        const f4 ci = c4[base];
        f4 o;
        #pragma unroll
        for (int d = 0; d < 4; ++d) {
            const float coup = (1.0f / (float)NN) * (ci[d] * accU[d] - si[d] * accV[d]);
            o[d] = th[d] + om[d] + kp[d] * (gm[d] - th[d]) + coup;
        }
        out4[base] = o;
    }
}

extern "C" void kernel_launch(void* const* d_in, const int* in_sizes, int n_in,
                              void* d_out, int out_size, void* d_ws, size_t ws_size,
                              hipStream_t stream) {
    const float* theta = (const float*)d_in[0];
    const float* gam   = (const float*)d_in[1];
    const float* aff   = (const float*)d_in[2];
    const float* alp   = (const float*)d_in[3];
    const float* omega = (const float*)d_in[4];
    const float* kappa = (const float*)d_in[5];
    const float* bias  = (const float*)d_in[6];
    float* out  = (float*)d_out;

    float* sArr = (float*)d_ws;                          // [B*N*D] fp32
    float* cArr = sArr + BB * NN * DD;                   // [B*N*D] fp32
    h8*    scT  = (h8*)(cArr + BB * NN * DD);            // [B][4][QQ] fp16 pairs, 128 KB

    precomp<<<(BB * QQ) / BLOCK, BLOCK, 0, stream>>>(theta, sArr, cArr, scT);
    kuramoto_main<<<BB * (NN / 4), BLOCK, 0, stream>>>(
        theta, gam, aff, alp, omega, kappa, bias, sArr, cArr, scT, out);
}